// Round 1
// baseline (146.294 us; speedup 1.0000x reference)
//
#include <hip/hip_runtime.h>
#include <hip/hip_bf16.h>

#define EPS 1e-5f

typedef unsigned short u16;
typedef __attribute__((ext_vector_type(8))) __bf16 bf16x8;
typedef __attribute__((ext_vector_type(4))) float f32x4;
typedef __attribute__((ext_vector_type(8))) short short8;

// round-to-nearest-even f32 -> bf16
__device__ __forceinline__ u16 f2bf(float f) {
  unsigned int u = __float_as_uint(f);
  u += 0x7fffu + ((u >> 16) & 1u);
  return (u16)(u >> 16);
}

// ---------------------------------------------------------------------------
// Fold BN into G layers 1,2 -> bf16 weights [out][in] + fp32 bias
// grid(16,2) block(256): blockIdx.y = layer-1, 16 rows per block.x
// ---------------------------------------------------------------------------
__global__ void fold_g(const float* __restrict__ gW, const float* __restrict__ gb,
                       const float* __restrict__ ggamma, const float* __restrict__ gbeta,
                       const float* __restrict__ gmean, const float* __restrict__ gvar,
                       u16* __restrict__ Wb, float* __restrict__ biasOut) {
  const int l = blockIdx.y;      // 0,1 -> g layer 1,2
  const int gl = l + 1;
  const int t = threadIdx.x;
  const int row = blockIdx.x * 16 + (t >> 4);
  const int c0 = (t & 15) * 16;
  const int gi = gl * 256 + row;
  const float s = ggamma[gi] * rsqrtf(gvar[gi] + EPS);
  if (c0 == 0) biasOut[l * 256 + row] = (gb[gi] - gmean[gi]) * s + gbeta[gi];
  const float* wrow = gW + (size_t)gi * 256;
  u16* orow = Wb + (size_t)l * 65536 + row * 256;
  #pragma unroll
  for (int c = 0; c < 16; ++c) orow[c0 + c] = f2bf(wrow[c0 + c] * s);
}

// ---------------------------------------------------------------------------
// L/R projections for layer 0 with BN fold:
//   L[b,n,u] = s0[u]*(W0[u,0:128]  . x[b,n]) + ((b0-mean)*s0+beta)[u]
//   R[b,n,u] = s0[u]*(W0[u,128:256]. x[b,n])
// grid(4,32) block(256): 16 objects per block
// ---------------------------------------------------------------------------
__global__ __launch_bounds__(256) void lr_kernel(
    const float* __restrict__ x, const float* __restrict__ gW,
    const float* __restrict__ gb, const float* __restrict__ ggamma,
    const float* __restrict__ gbeta, const float* __restrict__ gmean,
    const float* __restrict__ gvar,
    float* __restrict__ Lf, float* __restrict__ Rf) {
  const int b = blockIdx.y;
  const int chunk = blockIdx.x;          // 4 chunks of 16 objects
  __shared__ __align__(16) float xs[16][128];
  const int t = threadIdx.x;
  // stage x[b][chunk*16 .. +15][:]  (2048 floats)
  {
    const float4* src = (const float4*)(x + ((size_t)b * 64 + chunk * 16) * 128);
    float4* dst = (float4*)(&xs[0][0]);
    for (int idx = t; idx < 512; idx += 256) dst[idx] = src[idx];
  }
  __syncthreads();
  const int u = t;
  float accL[16], accR[16];
  #pragma unroll
  for (int nn = 0; nn < 16; ++nn) { accL[nn] = 0.f; accR[nn] = 0.f; }
  const float4* wl = (const float4*)(gW + (size_t)u * 256);
  const float4* wr = (const float4*)(gW + (size_t)u * 256 + 128);
  for (int d4 = 0; d4 < 32; ++d4) {
    const float4 a = wl[d4];
    const float4 c = wr[d4];
    #pragma unroll
    for (int nn = 0; nn < 16; ++nn) {
      const float4 xv = *((const float4*)&xs[nn][d4 * 4]);
      accL[nn] += a.x * xv.x + a.y * xv.y + a.z * xv.z + a.w * xv.w;
      accR[nn] += c.x * xv.x + c.y * xv.y + c.z * xv.z + c.w * xv.w;
    }
  }
  const float s = ggamma[u] * rsqrtf(gvar[u] + EPS);
  const float lb = (gb[u] - gmean[u]) * s + gbeta[u];
  const int n0 = chunk * 16;
  #pragma unroll
  for (int nn = 0; nn < 16; ++nn) {
    Lf[((size_t)b * 64 + n0 + nn) * 256 + u] = accL[nn] * s + lb;
    Rf[((size_t)b * 64 + n0 + nn) * 256 + u] = accR[nn] * s;
  }
}

// ---------------------------------------------------------------------------
// Main fused kernel: per (i, b): 64 pairs (i, j=0..63)
//   h1 = relu(L_i + R_j)            -> LDS bf16 (XOR-swizzled)
//   h2 = relu(W1b h1 + b1)          -> LDS bf16
//   h3 = relu(W2b h2 + b2)          -> column-sum over pairs -> atomicAdd S[b]
// block = 256 threads = 4 waves; wave w owns output cols [w*64, w*64+64)
// MFMA 16x16x32 bf16: A = pairs x K, B = W^T fragments straight from global.
// ---------------------------------------------------------------------------
__global__ __launch_bounds__(256) void rn_main(
    const float* __restrict__ Lf, const float* __restrict__ Rf,
    const u16* __restrict__ W1b, const u16* __restrict__ W2b,
    const float* __restrict__ biasg, float* __restrict__ S) {
  __shared__ __align__(16) u16 h0[64 * 256];
  __shared__ __align__(16) u16 h1[64 * 256];
  char* h0b = (char*)h0;
  char* h1b = (char*)h1;
  const int b = blockIdx.y;
  const int i = blockIdx.x;
  const int t = threadIdx.x;
  const int wave = t >> 6;
  const int lane = t & 63;
  const int g = lane >> 4;
  const int r = lane & 15;

  // ---- Phase 0: assemble h0[j][u] = relu(L[i][u] + R[j][u]) (bf16, swizzled)
  {
    const int j = t >> 2;
    const int c0 = (t & 3) * 64;
    const float4* lrow = (const float4*)(Lf + ((size_t)b * 64 + i) * 256 + c0);
    const float4* rrow = (const float4*)(Rf + ((size_t)b * 64 + j) * 256 + c0);
    const int swz = (j & 7) << 4;
    #pragma unroll
    for (int q = 0; q < 16; q += 2) {
      const float4 l0 = lrow[q];
      const float4 l1 = lrow[q + 1];
      const float4 r0 = rrow[q];
      const float4 r1 = rrow[q + 1];
      short8 pk;
      pk[0] = (short)f2bf(fmaxf(l0.x + r0.x, 0.f));
      pk[1] = (short)f2bf(fmaxf(l0.y + r0.y, 0.f));
      pk[2] = (short)f2bf(fmaxf(l0.z + r0.z, 0.f));
      pk[3] = (short)f2bf(fmaxf(l0.w + r0.w, 0.f));
      pk[4] = (short)f2bf(fmaxf(l1.x + r1.x, 0.f));
      pk[5] = (short)f2bf(fmaxf(l1.y + r1.y, 0.f));
      pk[6] = (short)f2bf(fmaxf(l1.z + r1.z, 0.f));
      pk[7] = (short)f2bf(fmaxf(l1.w + r1.w, 0.f));
      const int colb = (c0 + q * 4) * 2;
      *(short8*)(h0b + (j * 512 + (colb ^ swz))) = pk;
    }
  }
  __syncthreads();

  const int kl = g * 8;
  const f32x4 zero4 = {0.f, 0.f, 0.f, 0.f};
  f32x4 acc[4][4];

  // ---- Layer A: h0 -> h1 (weights W1b)
  {
    #pragma unroll
    for (int mt = 0; mt < 4; ++mt)
      #pragma unroll
      for (int nt = 0; nt < 4; ++nt) acc[mt][nt] = zero4;
    const bf16x8* wb = (const bf16x8*)W1b;
    #pragma unroll
    for (int kk = 0; kk < 8; ++kk) {
      const int k = kk * 32 + kl;
      bf16x8 bfrag[4];
      #pragma unroll
      for (int nt = 0; nt < 4; ++nt) {
        const int uo = wave * 64 + nt * 16 + r;
        bfrag[nt] = wb[uo * 32 + (k >> 3)];
      }
      #pragma unroll
      for (int mt = 0; mt < 4; ++mt) {
        const int row = mt * 16 + r;
        const bf16x8 afrag =
            *(const bf16x8*)(h0b + (row * 512 + ((k * 2) ^ ((row & 7) << 4))));
        #pragma unroll
        for (int nt = 0; nt < 4; ++nt)
          acc[mt][nt] = __builtin_amdgcn_mfma_f32_16x16x32_bf16(
              afrag, bfrag[nt], acc[mt][nt], 0, 0, 0);
      }
    }
    #pragma unroll
    for (int nt = 0; nt < 4; ++nt) {
      const int col = wave * 64 + nt * 16 + r;
      const float bias = biasg[col];
      #pragma unroll
      for (int mt = 0; mt < 4; ++mt) {
        #pragma unroll
        for (int reg = 0; reg < 4; ++reg) {
          const int row = mt * 16 + g * 4 + reg;
          const float v = fmaxf(acc[mt][nt][reg] + bias, 0.f);
          *(u16*)(h1b + (row * 512 + ((col * 2) ^ ((row & 7) << 4)))) = f2bf(v);
        }
      }
    }
  }
  __syncthreads();

  // ---- Layer B: h1 -> relu -> column sums -> atomic S
  {
    #pragma unroll
    for (int mt = 0; mt < 4; ++mt)
      #pragma unroll
      for (int nt = 0; nt < 4; ++nt) acc[mt][nt] = zero4;
    const bf16x8* wb = (const bf16x8*)W2b;
    #pragma unroll
    for (int kk = 0; kk < 8; ++kk) {
      const int k = kk * 32 + kl;
      bf16x8 bfrag[4];
      #pragma unroll
      for (int nt = 0; nt < 4; ++nt) {
        const int uo = wave * 64 + nt * 16 + r;
        bfrag[nt] = wb[uo * 32 + (k >> 3)];
      }
      #pragma unroll
      for (int mt = 0; mt < 4; ++mt) {
        const int row = mt * 16 + r;
        const bf16x8 afrag =
            *(const bf16x8*)(h1b + (row * 512 + ((k * 2) ^ ((row & 7) << 4))));
        #pragma unroll
        for (int nt = 0; nt < 4; ++nt)
          acc[mt][nt] = __builtin_amdgcn_mfma_f32_16x16x32_bf16(
              afrag, bfrag[nt], acc[mt][nt], 0, 0, 0);
      }
    }
    #pragma unroll
    for (int nt = 0; nt < 4; ++nt) {
      const int col = wave * 64 + nt * 16 + r;
      const float bias = biasg[256 + col];
      float cs = 0.f;
      #pragma unroll
      for (int mt = 0; mt < 4; ++mt)
        #pragma unroll
        for (int reg = 0; reg < 4; ++reg)
          cs += fmaxf(acc[mt][nt][reg] + bias, 0.f);
      cs += __shfl_xor(cs, 16, 64);
      cs += __shfl_xor(cs, 32, 64);
      if (lane < 16) atomicAdd(&S[(size_t)b * 256 + col], cs);
    }
  }
}

// ---------------------------------------------------------------------------
// F head: per batch, fp32: 2x (Linear+BN+ReLU) then Linear(256->128)
// ---------------------------------------------------------------------------
__global__ __launch_bounds__(256) void head_kernel(
    const float* __restrict__ S, const float* __restrict__ fW,
    const float* __restrict__ fb, const float* __restrict__ fgamma,
    const float* __restrict__ fbeta, const float* __restrict__ fmean,
    const float* __restrict__ fvar, const float* __restrict__ foW,
    const float* __restrict__ fob, float* __restrict__ out) {
  const int b = blockIdx.x;
  const int u = threadIdx.x;
  __shared__ __align__(16) float h[256];
  h[u] = S[(size_t)b * 256 + u];
  __syncthreads();
  for (int l = 0; l < 2; ++l) {
    const float4* wrow = (const float4*)(fW + ((size_t)l * 256 + u) * 256);
    float z = 0.f;
    #pragma unroll 8
    for (int q = 0; q < 64; ++q) {
      const float4 wv = wrow[q];
      const float4 hv = *((const float4*)&h[q * 4]);
      z += wv.x * hv.x + wv.y * hv.y + wv.z * hv.z + wv.w * hv.w;
    }
    z += fb[l * 256 + u];
    const int fi = l * 256 + u;
    const float s = fgamma[fi] * rsqrtf(fvar[fi] + EPS);
    z = (z - fmean[fi]) * s + fbeta[fi];
    z = fmaxf(z, 0.f);
    __syncthreads();
    h[u] = z;
    __syncthreads();
  }
  if (u < 128) {
    const float4* wrow = (const float4*)(foW + (size_t)u * 256);
    float z = 0.f;
    #pragma unroll 8
    for (int q = 0; q < 64; ++q) {
      const float4 wv = wrow[q];
      const float4 hv = *((const float4*)&h[q * 4]);
      z += wv.x * hv.x + wv.y * hv.y + wv.z * hv.z + wv.w * hv.w;
    }
    out[(size_t)b * 128 + u] = z + fob[u];
  }
}

extern "C" void kernel_launch(void* const* d_in, const int* in_sizes, int n_in,
                              void* d_out, int out_size, void* d_ws, size_t ws_size,
                              hipStream_t stream) {
  const float* x      = (const float*)d_in[0];
  const float* gW     = (const float*)d_in[1];
  const float* gb     = (const float*)d_in[2];
  const float* ggamma = (const float*)d_in[3];
  const float* gbeta  = (const float*)d_in[4];
  const float* gmean  = (const float*)d_in[5];
  const float* gvar   = (const float*)d_in[6];
  const float* fW     = (const float*)d_in[7];
  const float* fb     = (const float*)d_in[8];
  const float* fgamma = (const float*)d_in[9];
  const float* fbeta  = (const float*)d_in[10];
  const float* fmean  = (const float*)d_in[11];
  const float* fvar   = (const float*)d_in[12];
  const float* foW    = (const float*)d_in[13];
  const float* fob    = (const float*)d_in[14];

  // workspace layout
  u16* W1b = (u16*)d_ws;                 // 65536 bf16
  u16* W2b = W1b + 65536;                // 65536 bf16
  float* biasg = (float*)(W2b + 65536);  // 512 f32
  float* S = biasg + 512;                // 32*256 f32
  float* Lfp = S + 32 * 256;             // 32*64*256 f32
  float* Rfp = Lfp + 32 * 64 * 256;      // 32*64*256 f32

  hipMemsetAsync(S, 0, 32 * 256 * sizeof(float), stream);
  fold_g<<<dim3(16, 2), 256, 0, stream>>>(gW, gb, ggamma, gbeta, gmean, gvar,
                                          W1b, biasg);
  lr_kernel<<<dim3(4, 32), 256, 0, stream>>>(x, gW, gb, ggamma, gbeta, gmean,
                                             gvar, Lfp, Rfp);
  rn_main<<<dim3(64, 32), 256, 0, stream>>>(Lfp, Rfp, W1b, W2b, biasg, S);
  head_kernel<<<dim3(32), 256, 0, stream>>>(S, fW, fb, fgamma, fbeta, fmean,
                                            fvar, foW, fob, (float*)d_out);
}